// Round 14
// baseline (297.078 us; speedup 1.0000x reference)
//
#include <hip/hip_runtime.h>

typedef _Float16 half_t;
typedef half_t h8 __attribute__((ext_vector_type(8)));
typedef float f32x4 __attribute__((ext_vector_type(4)));
typedef unsigned int uint;
typedef unsigned long long ull;
typedef unsigned short ushort;

__device__ __forceinline__ float lrelu_f(float x){ return x >= 0.f ? x : 0.1f*x; }

__device__ __forceinline__ uint pack_h2(float a, float b){
  unsigned short lo = __builtin_bit_cast(unsigned short, (half_t)a);
  unsigned short hi = __builtin_bit_cast(unsigned short, (half_t)b);
  return (uint)lo | ((uint)hi << 16);
}
__device__ __forceinline__ h8 as_h8(uint4 v){ return __builtin_bit_cast(h8, v); }

enum { EPI_INIT=0, EPI_LRELU=1, EPI_LRELU_L2=2, EPI_L2=3 };
constexpr int CAP = 64;      // per-node CSR capacity (Poisson(16) max deg << 64)
constexpr int CHUNK = 4096;  // edges per binA block
constexpr int OSTR = 1056;   // offs stride (ushort) per chunk

// ---------- weight pre-pack into MFMA B-fragment order (f32 -> f16) ----------
__global__ void pack_all_kernel(const float* __restrict__ s0, half_t* __restrict__ d0,
                                const float* __restrict__ s1, half_t* __restrict__ d1,
                                const float* __restrict__ s2, half_t* __restrict__ d2,
                                const float* __restrict__ s3, half_t* __restrict__ d3,
                                const float* __restrict__ s4, half_t* __restrict__ d4){
  int b = blockIdx.x;
  const float* w; half_t* o; int K, M;
  if      (b < 8)  { w=s0; o=d0; K=256; M=64;  }
  else if (b < 24) { w=s1; o=d1; K=128; M=256; b-=8; }
  else if (b < 32) { w=s2; o=d2; K=256; M=64;  b-=24; }
  else if (b < 68) { w=s3; o=d3; K=192; M=384; b-=32; }
  else             { w=s4; o=d4; K=384; M=64;  b-=68; }
  int idx = b*256 + threadIdx.x;
  int total = (K/32)*(M/16)*64;
  if (idx >= total) return;
  int lane = idx & 63;
  int t = idx >> 6;
  int CBn = M/16;
  int cb = t % CBn;
  int s  = t / CBn;
  int k0 = s*32 + (lane>>4)*8;
  int c  = cb*16 + (lane&15);
  #pragma unroll
  for (int j=0;j<8;++j) o[(size_t)idx*8 + j] = (half_t)w[(size_t)(k0+j)*M + c];
}

// ---------- phase A: per-chunk bucket-sort (LDS hist + scan), compacted staging ----------
__global__ __launch_bounds__(256) void binA_kernel(const int* __restrict__ src, const int* __restrict__ dst,
    ull* __restrict__ staging, ushort* __restrict__ offs, int E, int nb){
  __shared__ int hist[1024];
  __shared__ int cursor[1024];
  int c = blockIdx.x;
  int base = c * CHUNK;
  for (int j = threadIdx.x; j < 1024; j += 256) hist[j] = 0;
  __syncthreads();
  #pragma unroll
  for (int it=0; it<CHUNK/256; ++it){
    int i = base + it*256 + threadIdx.x;
    if (i < E) atomicAdd(&hist[dst[i] >> 7], 1);
  }
  __syncthreads();
  for (int off=1; off<1024; off<<=1){
    int v[4];
    #pragma unroll
    for (int k=0;k<4;++k){
      int j = threadIdx.x + k*256;
      v[k] = (j>=off)? hist[j-off] : 0;
    }
    __syncthreads();
    #pragma unroll
    for (int k=0;k<4;++k) hist[threadIdx.x + k*256] += v[k];
    __syncthreads();
  }
  for (int j = threadIdx.x; j < 1024; j += 256){
    int ex = j ? hist[j-1] : 0;
    cursor[j] = ex;
    if (j <= nb) offs[(size_t)c*OSTR + j] = (ushort)ex;
  }
  __syncthreads();
  #pragma unroll
  for (int it=0; it<CHUNK/256; ++it){
    int i = base + it*256 + threadIdx.x;
    if (i < E){
      int d = dst[i];
      int s = src[i];
      int pos = atomicAdd(&cursor[d >> 7], 1);
      staging[(size_t)c*CHUNK + pos] = ((ull)(uint)d << 32) | (uint)s;
    }
  }
}

// ---------- phase B: one block per 128-node bucket; sole writer of its col/cnt region ----------
__global__ __launch_bounds__(256) void scatB_kernel(const ull* __restrict__ staging,
    const ushort* __restrict__ offs, int* __restrict__ cnt, int* __restrict__ col,
    int nChunks, int n){
  __shared__ int lcnt[128];
  int b = blockIdx.x;
  int node0 = b << 7;
  if (threadIdx.x < 128) lcnt[threadIdx.x] = 0;
  __syncthreads();
  for (int c = threadIdx.x; c < nChunks; c += 256){
    const ushort* op = offs + (size_t)c*OSTR;
    int o0 = op[b], o1 = op[b+1];
    const ull* sp = staging + (size_t)c*CHUNK;
    for (int j = o0; j < o1; ++j){
      ull v = sp[j];
      int d = (int)(v >> 32);
      int s = (int)(uint)v;
      int r = atomicAdd(&lcnt[d & 127], 1);
      if (r < CAP) col[(size_t)d*CAP + r] = s;
    }
  }
  __syncthreads();
  if (threadIdx.x < 128){
    int node = node0 + threadIdx.x;
    if (node < n) cnt[node] = lcnt[threadIdx.x];
  }
}

// ---------- init GEMM: all A-fragments preloaded ----------
template<int K, int MOUT, int EPI>
__global__ __launch_bounds__(256) void gemm_kernel(
  const float* __restrict__ x0, int st0,
  const half_t* __restrict__ wp, const float* __restrict__ bias,
  half_t* __restrict__ outv, int ost,
  const float* __restrict__ emb, const int* __restrict__ nid, int n)
{
  constexpr int KS = K/32;
  constexpr int CB = MOUT/16;
  const int lane = threadIdx.x & 63;
  const int wid  = threadIdx.x >> 6;
  const int row0 = blockIdx.x*64 + wid*16;
  const int arow = row0 + (lane & 15);
  const int arowc = arow < n ? arow : n-1;
  const int khi = (lane>>4)*8;

  f32x4 areg[2*KS];
  #pragma unroll
  for (int s=0;s<KS;++s){
    int k0 = s*32 + khi;
    areg[2*s]   = *(const f32x4*)(x0 + (size_t)arowc*st0 + k0);
    areg[2*s+1] = *(const f32x4*)(x0 + (size_t)arowc*st0 + k0 + 4);
  }

  f32x4 acc[CB];
  #pragma unroll
  for (int cb=0;cb<CB;++cb) acc[cb] = (f32x4){0.f,0.f,0.f,0.f};

  #pragma unroll
  for (int s=0;s<KS;++s){
    h8 af;
    #pragma unroll
    for (int j=0;j<4;++j){ af[j]=(half_t)areg[2*s][j]; af[j+4]=(half_t)areg[2*s+1][j]; }
    const h8* wrow = (const h8*)wp + (size_t)(s*CB)*64 + lane;
    #pragma unroll
    for (int cb=0;cb<CB;++cb){
      h8 bf = wrow[cb*64];
      acc[cb] = __builtin_amdgcn_mfma_f32_16x16x32_f16(af, bf, acc[cb], 0,0,0);
    }
  }

  const int cgrp = lane >> 4;
  const int ccol = lane & 15;
  #pragma unroll
  for (int r=0;r<4;++r){
    int R = row0 + cgrp*4 + r;
    if (R < n){
      #pragma unroll
      for (int cb=0;cb<CB;++cb){
        float t = lrelu_f(acc[cb][r] + bias[cb*16+ccol]);
        if constexpr (EPI==EPI_INIT) t += emb[(size_t)(nid[R]+1)*64 + cb*16 + ccol];
        outv[(size_t)R*ost + cb*16 + ccol] = (half_t)t;
      }
    }
  }
}

// ---------- fused gather + 2-layer MLP, 32 rows/block ----------
// GL=0: gather from h0 (128B rows) -> hagg LDS tile + hres -> global hc upper half.
// GL=1: gather from hc (256B rows) -> hagg + hsum LDS tiles.
// Stage-1 A-fragments for isrc>=1 read from the LDS tiles ([32][72] f16, 2-way max conflicts).
template<int GL, int K1, int M1, int M2, int EPI2, bool OUTF16>
__global__ __launch_bounds__(256,4) void mlpf_kernel(
  const half_t* __restrict__ x0, int st0,
  const uint* __restrict__ gsrc,
  const int* __restrict__ cnt, const int* __restrict__ col,
  const half_t* __restrict__ wp1, const float* __restrict__ b1,
  const half_t* __restrict__ wp2, const float* __restrict__ b2,
  void* __restrict__ outv, int ost,
  uint* __restrict__ hresOut, int n)
{
  constexpr int RS  = 17;
  constexpr int RSA = 72;                   // gather-tile row stride (f16): 144B -> 2-way max
  constexpr int KS1 = K1/32, CBT = M1/16, CBW = CBT/4;
  constexpr int KS2 = M1/32, CB2 = M2/16;
  constexpr int RED = 65;
  constexpr int TILEB = (GL==0 ? 1 : 2)*32*RSA*2;
  constexpr int REDB  = 2*16*RED*4;
  constexpr int OVLB  = TILEB > REDB ? TILEB : REDB;
  __shared__ uint  zc[M1*RS];
  __shared__ uint4 ovl[(OVLB+15)/16];       // gather tiles (phase 0/1) overlaid with red (phase 2)
  half_t* haggT = (half_t*)ovl;
  half_t* hsumT = (half_t*)ovl + 32*RSA;
  float*  red   = (float*)ovl;

  const int lane = threadIdx.x & 63;
  const int wid  = threadIdx.x >> 6;
  const int row0 = blockIdx.x*32;
  const int khi  = (lane>>4)*8;
  const int ccol = lane & 15;
  const int cgrp = lane >> 4;

  // ---- phase 0: gather this block's 32 nodes ----
  if constexpr (GL==0){
    const int g8 = lane >> 3, l8 = lane & 7;
    for (int pass=0; pass<8; ++pass){
      int node = row0 + pass*4 + wid;
      if (node < n){
        int deg = cnt[node];
        int degc = deg < CAP ? deg : CAP;
        const int* cv = col + (size_t)node*CAP;
        float a[8] = {0,0,0,0,0,0,0,0};
        int j = g8;
        for (; j + 8 < degc; j += 16){
          int c0 = cv[j], c1 = cv[j+8];
          uint4 v0 = *(const uint4*)(gsrc + (size_t)c0*32 + l8*4);
          uint4 v1 = *(const uint4*)(gsrc + (size_t)c1*32 + l8*4);
          h8 s = as_h8(v0) + as_h8(v1);
          #pragma unroll
          for (int q=0;q<8;++q) a[q] += (float)s[q];
        }
        if (j < degc){
          uint4 v = *(const uint4*)(gsrc + (size_t)cv[j]*32 + l8*4);
          h8 s = as_h8(v);
          #pragma unroll
          for (int q=0;q<8;++q) a[q] += (float)s[q];
        }
        #pragma unroll
        for (int q=0;q<8;++q){
          a[q] += __shfl_xor(a[q], 8);
          a[q] += __shfl_xor(a[q], 16);
          a[q] += __shfl_xor(a[q], 32);
        }
        uint4 hv4 = *(const uint4*)(gsrc + (size_t)node*32 + l8*4);
        h8 hvh = as_h8(hv4);
        float iwd = 1.f / fmaxf((float)deg - 1.f, 1.f);
        float sq = 0.f;
        #pragma unroll
        for (int q=0;q<8;++q){ a[q] = (a[q]-(float)hvh[q])*iwd; sq += a[q]*a[q]; }
        sq += __shfl_xor(sq,1); sq += __shfl_xor(sq,2); sq += __shfl_xor(sq,4);
        float inv = 1.f / fmaxf(sqrtf(sq), 1e-6f);
        if (g8 == 0){
          int lrow = pass*4 + wid;
          uint4 oa, oh;
          oa.x = pack_h2(a[0],a[1]); oa.y = pack_h2(a[2],a[3]);
          oa.z = pack_h2(a[4],a[5]); oa.w = pack_h2(a[6],a[7]);
          oh.x = pack_h2(a[0]*inv,a[1]*inv); oh.y = pack_h2(a[2]*inv,a[3]*inv);
          oh.z = pack_h2(a[4]*inv,a[5]*inv); oh.w = pack_h2(a[6]*inv,a[7]*inv);
          *(uint4*)(haggT + (size_t)lrow*RSA + l8*8) = oa;
          *(uint4*)(hresOut + (size_t)node*64 + 32 + l8*4) = oh;
        }
      }
    }
  } else {
    const int g16 = lane >> 4, l16 = lane & 15;
    for (int pass=0; pass<8; ++pass){
      int node = row0 + pass*4 + wid;
      if (node < n){
        int deg = cnt[node];
        int degc = deg < CAP ? deg : CAP;
        const int* cv = col + (size_t)node*CAP;
        float a[8] = {0,0,0,0,0,0,0,0};
        int j = g16;
        for (; j + 12 < degc; j += 16){
          int c0 = cv[j], c1 = cv[j+4], c2 = cv[j+8], c3 = cv[j+12];
          uint4 v0 = *(const uint4*)(gsrc + (size_t)c0*64 + l16*4);
          uint4 v1 = *(const uint4*)(gsrc + (size_t)c1*64 + l16*4);
          uint4 v2 = *(const uint4*)(gsrc + (size_t)c2*64 + l16*4);
          uint4 v3 = *(const uint4*)(gsrc + (size_t)c3*64 + l16*4);
          h8 s = (as_h8(v0) + as_h8(v1)) + (as_h8(v2) + as_h8(v3));
          #pragma unroll
          for (int q=0;q<8;++q) a[q] += (float)s[q];
        }
        for (; j < degc; j += 4){
          uint4 v = *(const uint4*)(gsrc + (size_t)cv[j]*64 + l16*4);
          h8 s = as_h8(v);
          #pragma unroll
          for (int q=0;q<8;++q) a[q] += (float)s[q];
        }
        #pragma unroll
        for (int q=0;q<8;++q){
          a[q] += __shfl_xor(a[q], 16);
          a[q] += __shfl_xor(a[q], 32);
        }
        if (g16 == 0){
          int lrow = pass*4 + wid;
          if (l16 < 8){
            uint4 hv4 = *(const uint4*)(gsrc + (size_t)node*64 + l16*4);
            h8 hvh = as_h8(hv4);
            float iwd = 1.f / fmaxf((float)deg - 1.f, 1.f);
            uint4 o;
            o.x = pack_h2((a[0]-(float)hvh[0])*iwd,(a[1]-(float)hvh[1])*iwd);
            o.y = pack_h2((a[2]-(float)hvh[2])*iwd,(a[3]-(float)hvh[3])*iwd);
            o.z = pack_h2((a[4]-(float)hvh[4])*iwd,(a[5]-(float)hvh[5])*iwd);
            o.w = pack_h2((a[6]-(float)hvh[6])*iwd,(a[7]-(float)hvh[7])*iwd);
            *(uint4*)(haggT + (size_t)lrow*RSA + l16*8) = o;
          } else {
            uint4 o;
            o.x = pack_h2(a[0],a[1]); o.y = pack_h2(a[2],a[3]);
            o.z = pack_h2(a[4],a[5]); o.w = pack_h2(a[6],a[7]);
            *(uint4*)(hsumT + (size_t)lrow*RSA + (l16-8)*8) = o;
          }
        }
      }
    }
  }
  __syncthreads();

  // ---- stage 1 ----
  f32x4 acc[2][CBW];
  #pragma unroll
  for (int t=0;t<2;++t)
    #pragma unroll
    for (int cb=0;cb<CBW;++cb) acc[t][cb] = (f32x4){0.f,0.f,0.f,0.f};

  #pragma unroll
  for (int s=0;s<KS1;++s){
    int k0 = s*32 + khi;
    int isrc = k0 >> 6;
    int koff = k0 & 63;
    h8 af[2];
    #pragma unroll
    for (int t=0;t<2;++t){
      int lr = t*16 + ccol;
      if (isrc == 0){
        int ar = row0 + lr; if (ar >= n) ar = n-1;
        af[t] = *(const h8*)(x0 + (size_t)ar*st0 + koff);
      } else if (isrc == 1){
        af[t] = *(const h8*)(haggT + (size_t)lr*RSA + koff);
      } else {
        af[t] = *(const h8*)(hsumT + (size_t)lr*RSA + koff);
      }
    }
    #pragma unroll
    for (int cb=0;cb<CBW;++cb){
      h8 bf = ((const h8*)wp1)[(size_t)(s*CBT + wid*CBW + cb)*64 + lane];
      #pragma unroll
      for (int t=0;t<2;++t)
        acc[t][cb] = __builtin_amdgcn_mfma_f32_16x16x32_f16(af[t], bf, acc[t][cb], 0,0,0);
    }
  }
  #pragma unroll
  for (int t=0;t<2;++t){
    #pragma unroll
    for (int cb=0;cb<CBW;++cb){
      int colx = wid*(CBW*16) + cb*16 + ccol;
      float bb = b1[colx];
      float v0 = lrelu_f(acc[t][cb][0]+bb);
      float v1 = lrelu_f(acc[t][cb][1]+bb);
      float v2 = lrelu_f(acc[t][cb][2]+bb);
      float v3 = lrelu_f(acc[t][cb][3]+bb);
      int idx = colx*RS + t*8 + cgrp*2;
      zc[idx]   = pack_h2(v0,v1);
      zc[idx+1] = pack_h2(v2,v3);
    }
  }
  __syncthreads();

  // ---- stage 2 (red overlays the gather tiles; tiles dead after stage 1) ----
  const int rt = wid & 1, kh = wid >> 1;
  f32x4 acc2[CB2];
  #pragma unroll
  for (int cb=0;cb<CB2;++cb) acc2[cb] = (f32x4){0.f,0.f,0.f,0.f};
  const uint sel = (lane&1) ? 0x07060302u : 0x05040100u;
  const int rp0 = rt*8 + (ccol>>1);

  #pragma unroll
  for (int si=0;si<KS2/2;++si){
    int s = kh*(KS2/2) + si;
    uint v[8];
    #pragma unroll
    for (int j=0;j<8;++j) v[j] = zc[(s*32 + khi + j)*RS + rp0];
    uint4 u;
    u.x = __builtin_amdgcn_perm(v[1], v[0], sel);
    u.y = __builtin_amdgcn_perm(v[3], v[2], sel);
    u.z = __builtin_amdgcn_perm(v[5], v[4], sel);
    u.w = __builtin_amdgcn_perm(v[7], v[6], sel);
    h8 af2 = __builtin_bit_cast(h8, u);
    #pragma unroll
    for (int cb=0;cb<CB2;++cb){
      h8 bf = ((const h8*)wp2)[(size_t)(s*CB2+cb)*64 + lane];
      acc2[cb] = __builtin_amdgcn_mfma_f32_16x16x32_f16(af2, bf, acc2[cb], 0,0,0);
    }
  }
  if (kh == 1){
    #pragma unroll
    for (int cb=0;cb<CB2;++cb)
      #pragma unroll
      for (int r=0;r<4;++r)
        red[(rt*16 + cgrp*4 + r)*RED + cb*16 + ccol] = acc2[cb][r];
  }
  __syncthreads();
  if (kh == 0){
    #pragma unroll
    for (int r=0;r<4;++r){
      int Rr = row0 + rt*16 + cgrp*4 + r;
      float vv[CB2];
      #pragma unroll
      for (int cb=0;cb<CB2;++cb){
        float t = acc2[cb][r] + red[(rt*16 + cgrp*4 + r)*RED + cb*16 + ccol] + b2[cb*16+ccol];
        if constexpr (EPI2==EPI_LRELU_L2) t = lrelu_f(t);
        vv[cb] = t;
      }
      float sq = 0.f;
      #pragma unroll
      for (int cb=0;cb<CB2;++cb) sq += vv[cb]*vv[cb];
      sq += __shfl_xor(sq,1); sq += __shfl_xor(sq,2);
      sq += __shfl_xor(sq,4); sq += __shfl_xor(sq,8);
      float inv = 1.f / fmaxf(sqrtf(sq), 1e-6f);
      if (Rr < n){
        #pragma unroll
        for (int cb=0;cb<CB2;++cb){
          float t = vv[cb]*inv;
          if constexpr (OUTF16)
            ((half_t*)outv)[(size_t)Rr*ost + cb*16 + ccol] = (half_t)t;
          else
            ((float*)outv)[(size_t)Rr*ost + cb*16 + ccol] = t;
        }
      }
    }
  }
}

extern "C" void kernel_launch(void* const* d_in, const int* in_sizes, int n_in,
                              void* d_out, int out_size, void* d_ws, size_t ws_size,
                              hipStream_t stream){
  const float* content = (const float*)d_in[0];
  const float* node_emb= (const float*)d_in[1];
  const float* proj_w  = (const float*)d_in[2];
  const float* proj_b  = (const float*)d_in[3];
  const float* c0w1 = (const float*)d_in[4];
  const float* c0b1 = (const float*)d_in[5];
  const float* c0w2 = (const float*)d_in[6];
  const float* c0b2 = (const float*)d_in[7];
  const float* c1w1 = (const float*)d_in[8];
  const float* c1b1 = (const float*)d_in[9];
  const float* c1w2 = (const float*)d_in[10];
  const float* c1b2 = (const float*)d_in[11];
  const int* nid = (const int*)d_in[12];
  const int* src = (const int*)d_in[13];
  const int* dst = (const int*)d_in[14];
  float* out = (float*)d_out;
  const int n = in_sizes[12];     // 100000
  const int E = in_sizes[13];     // 1600000

  char* ws = (char*)d_ws;
  size_t off = 0;
  auto alloc = [&](size_t bytes)->char*{
    char* p = ws + off;
    off = (off + bytes + 255) & ~(size_t)255;
    return p;
  };
  const int nChunks = (E + CHUNK - 1)/CHUNK;   // 391
  const int nb = (n + 127) >> 7;               // 782 buckets
  half_t* h0   = (half_t*)alloc((size_t)n*64*2);
  half_t* hc   = (half_t*)alloc((size_t)n*128*2);   // [hnew(64) || hres(64)]
  int* cnt    = (int*)alloc((size_t)n*4);
  int* col    = (int*)alloc((size_t)n*CAP*4);             // 25.6 MB
  ull* staging= (ull*)alloc((size_t)nChunks*CHUNK*8);     // 12.8 MB
  ushort* offs= (ushort*)alloc((size_t)nChunks*OSTR*2);   // 0.8 MB
  half_t* wp0 = (half_t*)alloc((size_t)256*64*2);
  half_t* wp1 = (half_t*)alloc((size_t)128*256*2);
  half_t* wp2 = (half_t*)alloc((size_t)256*64*2);
  half_t* wp3 = (half_t*)alloc((size_t)192*384*2);
  half_t* wp4 = (half_t*)alloc((size_t)384*64*2);

  pack_all_kernel<<<80,256,0,stream>>>(proj_w, wp0, c0w1, wp1, c0w2, wp2, c1w1, wp3, c1w2, wp4);

  // atomic-free CSR build
  binA_kernel<<<nChunks,256,0,stream>>>(src, dst, staging, offs, E, nb);
  scatB_kernel<<<nb,256,0,stream>>>(staging, offs, cnt, col, nChunks, n);

  const int rgrid = (n + 63)/64;
  const int mgrid = (n + 31)/32;

  gemm_kernel<256,64,EPI_INIT><<<rgrid,256,0,stream>>>(
      content, 256, wp0, proj_b, h0, 64, node_emb, nid, n);

  // layer 0: fused gather(h0) + MLP -> hnew into hc[:,0:64], hres into hc[:,64:128]
  mlpf_kernel<0,128,256,64,EPI_LRELU_L2,true><<<mgrid,256,0,stream>>>(
      h0, 64, (const uint*)h0, cnt, col, wp1, c0b1, wp2, c0b2, hc, 128, (uint*)hc, n);

  // layer 1: fused gather(hc) + MLP -> out (f32)
  mlpf_kernel<1,192,384,64,EPI_L2,false><<<mgrid,256,0,stream>>>(
      hc, 128, (const uint*)hc, cnt, col, wp3, c1b1, wp4, c1b2, out, 64, nullptr, n);
}

// Round 16
// 270.275 us; speedup vs baseline: 1.0992x; 1.0992x over previous
//
#include <hip/hip_runtime.h>

typedef _Float16 half_t;
typedef half_t h8 __attribute__((ext_vector_type(8)));
typedef float f32x4 __attribute__((ext_vector_type(4)));
typedef unsigned int uint;
typedef unsigned long long ull;
typedef unsigned short ushort;

__device__ __forceinline__ float lrelu_f(float x){ return x >= 0.f ? x : 0.1f*x; }

__device__ __forceinline__ uint pack_h2(float a, float b){
  unsigned short lo = __builtin_bit_cast(unsigned short, (half_t)a);
  unsigned short hi = __builtin_bit_cast(unsigned short, (half_t)b);
  return (uint)lo | ((uint)hi << 16);
}
__device__ __forceinline__ h8 as_h8(uint4 v){ return __builtin_bit_cast(h8, v); }

// f32 accumulate of both f16 halves of a packed u32 via v_fma_mix (1 instr per half)
__device__ __forceinline__ void acc_mix(float& lo, float& hi, uint pk, float one){
  asm("v_fma_mix_f32 %0, %1, %2, %0 op_sel:[0,0,0] op_sel_hi:[1,0,0]" : "+v"(lo) : "v"(pk), "v"(one));
  asm("v_fma_mix_f32 %0, %1, %2, %0 op_sel:[1,0,0] op_sel_hi:[1,0,0]" : "+v"(hi) : "v"(pk), "v"(one));
}

enum { EPI_INIT=0, EPI_LRELU=1, EPI_LRELU_L2=2, EPI_L2=3 };
constexpr int CAP = 64;      // per-node CSR capacity (Poisson(16) max deg << 64)
constexpr int CHUNK = 4096;  // edges per binA block
constexpr int OSTR = 1056;   // offs stride (ushort) per chunk

// ---------- dispatch 1: pack(80) + binA(nChunks). No in-dispatch consumers. ----------
__global__ __launch_bounds__(256) void front_kernel(
    const float* __restrict__ s0, half_t* __restrict__ d0,
    const float* __restrict__ s1, half_t* __restrict__ d1,
    const float* __restrict__ s2, half_t* __restrict__ d2,
    const float* __restrict__ s3, half_t* __restrict__ d3,
    const float* __restrict__ s4, half_t* __restrict__ d4,
    const int* __restrict__ src, const int* __restrict__ dst,
    ull* __restrict__ staging, ushort* __restrict__ offs, int E, int nbkt)
{
  __shared__ int hist[1024];
  __shared__ int cursor[1024];
  int b = blockIdx.x;

  if (b < 80){
    const float* w; half_t* o; int K, M;
    if      (b < 8)  { w=s0; o=d0; K=256; M=64;  }
    else if (b < 24) { w=s1; o=d1; K=128; M=256; b-=8; }
    else if (b < 32) { w=s2; o=d2; K=256; M=64;  b-=24; }
    else if (b < 68) { w=s3; o=d3; K=192; M=384; b-=32; }
    else             { w=s4; o=d4; K=384; M=64;  b-=68; }
    int idx = b*256 + threadIdx.x;
    int total = (K/32)*(M/16)*64;
    if (idx >= total) return;
    int lane = idx & 63;
    int t = idx >> 6;
    int CBn = M/16;
    int cb = t % CBn;
    int s  = t / CBn;
    int k0 = s*32 + (lane>>4)*8;
    int c  = cb*16 + (lane&15);
    #pragma unroll
    for (int j=0;j<8;++j) o[(size_t)idx*8 + j] = (half_t)w[(size_t)(k0+j)*M + c];
    return;
  }

  // ---- binA: per-chunk bucket sort into compacted staging ----
  int c = b - 80;
  int base = c * CHUNK;
  for (int j = threadIdx.x; j < 1024; j += 256) hist[j] = 0;
  __syncthreads();
  #pragma unroll
  for (int it=0; it<CHUNK/256; ++it){
    int i = base + it*256 + threadIdx.x;
    if (i < E) atomicAdd(&hist[dst[i] >> 7], 1);
  }
  __syncthreads();
  for (int off=1; off<1024; off<<=1){
    int v[4];
    #pragma unroll
    for (int k=0;k<4;++k){
      int j = threadIdx.x + k*256;
      v[k] = (j>=off)? hist[j-off] : 0;
    }
    __syncthreads();
    #pragma unroll
    for (int k=0;k<4;++k) hist[threadIdx.x + k*256] += v[k];
    __syncthreads();
  }
  for (int j = threadIdx.x; j < 1024; j += 256){
    int ex = j ? hist[j-1] : 0;
    cursor[j] = ex;
    if (j <= nbkt) offs[(size_t)c*OSTR + j] = (ushort)ex;
  }
  __syncthreads();
  #pragma unroll
  for (int it=0; it<CHUNK/256; ++it){
    int i = base + it*256 + threadIdx.x;
    if (i < E){
      int d = dst[i];
      int s = src[i];
      int pos = atomicAdd(&cursor[d >> 7], 1);
      staging[(size_t)c*CHUNK + pos] = ((ull)(uint)d << 32) | (uint)s;
    }
  }
}

// ---------- dispatch 2: scatB (1-in-3 blocks) || init-GEMM (rest). ----------
// scatB depends on binA (disp 1); gemm depends on wp0 (disp 1) -> race-free.
// scatB latency-bound (512B LDS), gemm HBM/MFMA-bound: true overlap.
__global__ __launch_bounds__(256) void mid_kernel(
    const ull* __restrict__ staging, const ushort* __restrict__ offs,
    int* __restrict__ cnt, int* __restrict__ col, int nChunks, int nbkt,
    const float* __restrict__ content, const half_t* __restrict__ wp0,
    const float* __restrict__ proj_b, const float* __restrict__ node_emb,
    const int* __restrict__ nid, half_t* __restrict__ h0, int n)
{
  __shared__ int lcnt[128];
  int b = blockIdx.x;
  int m3 = b/3;
  int scatBefore = (b%3==0) ? m3 : m3+1;
  if (scatBefore > nbkt) scatBefore = nbkt;
  bool isScat = (b%3==0) && (m3 < nbkt);

  if (isScat){
    int bk = m3;
    int node0 = bk << 7;
    if (threadIdx.x < 128) lcnt[threadIdx.x] = 0;
    __syncthreads();
    for (int c = threadIdx.x; c < nChunks; c += 256){
      const ushort* op = offs + (size_t)c*OSTR;
      int o0 = op[bk], o1 = op[bk+1];
      const ull* sp = staging + (size_t)c*CHUNK;
      for (int j = o0; j < o1; ++j){
        ull v = sp[j];
        int d = (int)(v >> 32);
        int s = (int)(uint)v;
        int r = atomicAdd(&lcnt[d & 127], 1);
        if (r < CAP) col[(size_t)d*CAP + r] = s;
      }
    }
    __syncthreads();
    if (threadIdx.x < 128){
      int node = node0 + threadIdx.x;
      if (node < n) cnt[node] = lcnt[threadIdx.x];
    }
    return;
  }

  // ---- init GEMM (64 rows, A preloaded 16 deep) ----
  int gb = b - scatBefore;
  const int lane = threadIdx.x & 63;
  const int wid  = threadIdx.x >> 6;
  const int row0 = gb*64 + wid*16;
  const int arow = row0 + (lane & 15);
  const int arowc = arow < n ? arow : n-1;
  const int khi = (lane>>4)*8;

  f32x4 areg[16];
  #pragma unroll
  for (int s=0;s<8;++s){
    uint k0 = (uint)arowc*256u + (uint)(s*32 + khi);
    areg[2*s]   = *(const f32x4*)(content + k0);
    areg[2*s+1] = *(const f32x4*)(content + k0 + 4);
  }

  f32x4 acc[4];
  #pragma unroll
  for (int cb=0;cb<4;++cb) acc[cb] = (f32x4){0.f,0.f,0.f,0.f};

  #pragma unroll
  for (int s=0;s<8;++s){
    h8 af;
    #pragma unroll
    for (int j=0;j<4;++j){ af[j]=(half_t)areg[2*s][j]; af[j+4]=(half_t)areg[2*s+1][j]; }
    const h8* wrow = (const h8*)wp0 + (size_t)(s*4)*64 + lane;
    #pragma unroll
    for (int cb=0;cb<4;++cb){
      h8 bf = wrow[cb*64];
      acc[cb] = __builtin_amdgcn_mfma_f32_16x16x32_f16(af, bf, acc[cb], 0,0,0);
    }
  }

  const int cgrp = lane >> 4;
  const int ccol = lane & 15;
  #pragma unroll
  for (int r=0;r<4;++r){
    int R = row0 + cgrp*4 + r;
    if (R < n){
      #pragma unroll
      for (int cb=0;cb<4;++cb){
        float t = lrelu_f(acc[cb][r] + proj_b[cb*16+ccol]);
        t += node_emb[(size_t)(nid[R]+1)*64 + cb*16 + ccol];
        h0[(size_t)R*64 + cb*16 + ccol] = (half_t)t;
      }
    }
  }
}

// ---------- fused 2-layer MLP, 32 rows/block ----------
template<int K1, int M1, int M2, int NSRC, int EPI2, bool OUTF16>
__global__ __launch_bounds__(256,4) void mlp_kernel(
  const half_t* __restrict__ x0, const half_t* __restrict__ x1, const half_t* __restrict__ x2,
  int st0, int st1, int st2,
  const half_t* __restrict__ wp1, const float* __restrict__ b1,
  const half_t* __restrict__ wp2, const float* __restrict__ b2,
  void* __restrict__ outv, int ost, int n)
{
  constexpr int RS  = 17;
  constexpr int KS1 = K1/32, CBT = M1/16, CBW = CBT/4;
  constexpr int KS2 = M1/32, CB2 = M2/16;
  constexpr int RED = 65;
  __shared__ uint  zc[M1*RS];
  __shared__ float red[2*16*RED];

  const int lane = threadIdx.x & 63;
  const int wid  = threadIdx.x >> 6;
  const int row0 = blockIdx.x*32;
  const int khi  = (lane>>4)*8;
  const int ccol = lane & 15;
  const int cgrp = lane >> 4;

  // ---- stage 1 ----
  f32x4 acc[2][CBW];
  #pragma unroll
  for (int t=0;t<2;++t)
    #pragma unroll
    for (int cb=0;cb<CBW;++cb) acc[t][cb] = (f32x4){0.f,0.f,0.f,0.f};

  #pragma unroll
  for (int s=0;s<KS1;++s){
    int k0 = s*32 + khi;
    const half_t* p = x0; int st = st0; int koff = k0;
    if constexpr (NSRC>1){
      int isrc = k0 >> 6;
      if constexpr (NSRC>=2){ if (isrc==1){ p=x1; st=st1; } }
      if constexpr (NSRC>=3){ if (isrc==2){ p=x2; st=st2; } }
      koff = k0 & 63;
    }
    h8 af[2];
    #pragma unroll
    for (int t=0;t<2;++t){
      int ar = row0 + t*16 + ccol; if (ar >= n) ar = n-1;
      af[t] = *(const h8*)(p + (size_t)ar*st + koff);
    }
    #pragma unroll
    for (int cb=0;cb<CBW;++cb){
      h8 bf = ((const h8*)wp1)[(size_t)(s*CBT + wid*CBW + cb)*64 + lane];
      #pragma unroll
      for (int t=0;t<2;++t)
        acc[t][cb] = __builtin_amdgcn_mfma_f32_16x16x32_f16(af[t], bf, acc[t][cb], 0,0,0);
    }
  }
  #pragma unroll
  for (int t=0;t<2;++t){
    #pragma unroll
    for (int cb=0;cb<CBW;++cb){
      int col = wid*(CBW*16) + cb*16 + ccol;
      float bb = b1[col];
      float v0 = lrelu_f(acc[t][cb][0]+bb);
      float v1 = lrelu_f(acc[t][cb][1]+bb);
      float v2 = lrelu_f(acc[t][cb][2]+bb);
      float v3 = lrelu_f(acc[t][cb][3]+bb);
      int idx = col*RS + t*8 + cgrp*2;
      zc[idx]   = pack_h2(v0,v1);
      zc[idx+1] = pack_h2(v2,v3);
    }
  }
  __syncthreads();

  // ---- stage 2 ----
  const int rt = wid & 1, kh = wid >> 1;
  f32x4 acc2[CB2];
  #pragma unroll
  for (int cb=0;cb<CB2;++cb) acc2[cb] = (f32x4){0.f,0.f,0.f,0.f};
  const uint sel = (lane&1) ? 0x07060302u : 0x05040100u;
  const int rp0 = rt*8 + (ccol>>1);

  #pragma unroll
  for (int si=0;si<KS2/2;++si){
    int s = kh*(KS2/2) + si;
    uint v[8];
    #pragma unroll
    for (int j=0;j<8;++j) v[j] = zc[(s*32 + khi + j)*RS + rp0];
    uint4 u;
    u.x = __builtin_amdgcn_perm(v[1], v[0], sel);
    u.y = __builtin_amdgcn_perm(v[3], v[2], sel);
    u.z = __builtin_amdgcn_perm(v[5], v[4], sel);
    u.w = __builtin_amdgcn_perm(v[7], v[6], sel);
    h8 af2 = __builtin_bit_cast(h8, u);
    #pragma unroll
    for (int cb=0;cb<CB2;++cb){
      h8 bf = ((const h8*)wp2)[(size_t)(s*CB2+cb)*64 + lane];
      acc2[cb] = __builtin_amdgcn_mfma_f32_16x16x32_f16(af2, bf, acc2[cb], 0,0,0);
    }
  }
  if (kh == 1){
    #pragma unroll
    for (int cb=0;cb<CB2;++cb)
      #pragma unroll
      for (int r=0;r<4;++r)
        red[(rt*16 + cgrp*4 + r)*RED + cb*16 + ccol] = acc2[cb][r];
  }
  __syncthreads();
  if (kh == 0){
    #pragma unroll
    for (int r=0;r<4;++r){
      int Rr = row0 + rt*16 + cgrp*4 + r;
      float vv[CB2];
      #pragma unroll
      for (int cb=0;cb<CB2;++cb){
        float t = acc2[cb][r] + red[(rt*16 + cgrp*4 + r)*RED + cb*16 + ccol] + b2[cb*16+ccol];
        if constexpr (EPI2==EPI_LRELU_L2) t = lrelu_f(t);
        vv[cb] = t;
      }
      float sq = 0.f;
      #pragma unroll
      for (int cb=0;cb<CB2;++cb) sq += vv[cb]*vv[cb];
      sq += __shfl_xor(sq,1); sq += __shfl_xor(sq,2);
      sq += __shfl_xor(sq,4); sq += __shfl_xor(sq,8);
      float inv = 1.f / fmaxf(sqrtf(sq), 1e-6f);
      if (Rr < n){
        #pragma unroll
        for (int cb=0;cb<CB2;++cb){
          float t = vv[cb]*inv;
          if constexpr (OUTF16)
            ((half_t*)outv)[(size_t)Rr*ost + cb*16 + ccol] = (half_t)t;
          else
            ((float*)outv)[(size_t)Rr*ost + cb*16 + ccol] = t;
        }
      }
    }
  }
}

// layer-0 gather: 2-deep, pk-f16 pair-add, fma_mix flush, 32-bit addressing.
__global__ __launch_bounds__(256) void segsum0_kernel(const uint* __restrict__ hu, const int* __restrict__ cnt,
                               const int* __restrict__ col,
                               uint* __restrict__ hagg, uint* __restrict__ hc, int n){
  int node = blockIdx.x*4 + (threadIdx.x>>6);
  if (node >= n) return;
  int lane = threadIdx.x & 63;
  int g = lane >> 3, l = lane & 7;
  int deg = cnt[node];
  int degc = deg < CAP ? deg : CAP;
  const int* cv = col + ((uint)node<<6);
  const float one = 1.0f;
  float a[8] = {0,0,0,0,0,0,0,0};
  int j = g;
  for (; j + 8 < degc; j += 16){
    uint c0 = (uint)cv[j], c1 = (uint)cv[j+8];
    uint4 v0 = *(const uint4*)(hu + (c0<<5) + (l<<2));
    uint4 v1 = *(const uint4*)(hu + (c1<<5) + (l<<2));
    uint4 su = __builtin_bit_cast(uint4, as_h8(v0) + as_h8(v1));
    acc_mix(a[0],a[1],su.x,one); acc_mix(a[2],a[3],su.y,one);
    acc_mix(a[4],a[5],su.z,one); acc_mix(a[6],a[7],su.w,one);
  }
  if (j < degc){
    uint c = (uint)cv[j];
    uint4 v = *(const uint4*)(hu + (c<<5) + (l<<2));
    acc_mix(a[0],a[1],v.x,one); acc_mix(a[2],a[3],v.y,one);
    acc_mix(a[4],a[5],v.z,one); acc_mix(a[6],a[7],v.w,one);
  }
  #pragma unroll
  for (int q=0;q<8;++q){
    a[q] += __shfl_xor(a[q], 8);
    a[q] += __shfl_xor(a[q], 16);
    a[q] += __shfl_xor(a[q], 32);
  }
  uint4 hv4 = *(const uint4*)(hu + ((uint)node<<5) + (l<<2));
  h8 hvh = as_h8(hv4);
  float iwd = 1.f / fmaxf((float)deg - 1.f, 1.f);
  float sq = 0.f;
  #pragma unroll
  for (int q=0;q<8;++q){ a[q] = (a[q]-(float)hvh[q])*iwd; sq += a[q]*a[q]; }
  sq += __shfl_xor(sq,1); sq += __shfl_xor(sq,2); sq += __shfl_xor(sq,4);
  float inv = 1.f / fmaxf(sqrtf(sq), 1e-6f);
  if (g == 0){
    uint4 oa, oh;
    oa.x = pack_h2(a[0],a[1]); oa.y = pack_h2(a[2],a[3]);
    oa.z = pack_h2(a[4],a[5]); oa.w = pack_h2(a[6],a[7]);
    oh.x = pack_h2(a[0]*inv,a[1]*inv); oh.y = pack_h2(a[2]*inv,a[3]*inv);
    oh.z = pack_h2(a[4]*inv,a[5]*inv); oh.w = pack_h2(a[6]*inv,a[7]*inv);
    *(uint4*)(hagg + ((uint)node<<5) + (l<<2)) = oa;
    *(uint4*)(hc + ((uint)node<<6) + 32 + (l<<2)) = oh;
  }
}

// layer-1 gather: 4-deep, pk-f16 tree, fma_mix flush, 32-bit addressing.
__global__ __launch_bounds__(256) void segsum1_kernel(const uint* __restrict__ hcu, const int* __restrict__ cnt,
                               const int* __restrict__ col,
                               uint* __restrict__ hagg, uint* __restrict__ hsum, int n){
  int node = blockIdx.x*4 + (threadIdx.x>>6);
  if (node >= n) return;
  int lane = threadIdx.x & 63;
  int g = lane >> 4, l = lane & 15;
  int deg = cnt[node];
  int degc = deg < CAP ? deg : CAP;
  const int* cv = col + ((uint)node<<6);
  const float one = 1.0f;
  float a[8] = {0,0,0,0,0,0,0,0};
  int j = g;
  for (; j + 12 < degc; j += 16){
    uint c0 = (uint)cv[j], c1 = (uint)cv[j+4], c2 = (uint)cv[j+8], c3 = (uint)cv[j+12];
    uint4 v0 = *(const uint4*)(hcu + (c0<<6) + (l<<2));
    uint4 v1 = *(const uint4*)(hcu + (c1<<6) + (l<<2));
    uint4 v2 = *(const uint4*)(hcu + (c2<<6) + (l<<2));
    uint4 v3 = *(const uint4*)(hcu + (c3<<6) + (l<<2));
    uint4 su = __builtin_bit_cast(uint4, (as_h8(v0) + as_h8(v1)) + (as_h8(v2) + as_h8(v3)));
    acc_mix(a[0],a[1],su.x,one); acc_mix(a[2],a[3],su.y,one);
    acc_mix(a[4],a[5],su.z,one); acc_mix(a[6],a[7],su.w,one);
  }
  for (; j < degc; j += 4){
    uint c = (uint)cv[j];
    uint4 v = *(const uint4*)(hcu + (c<<6) + (l<<2));
    acc_mix(a[0],a[1],v.x,one); acc_mix(a[2],a[3],v.y,one);
    acc_mix(a[4],a[5],v.z,one); acc_mix(a[6],a[7],v.w,one);
  }
  #pragma unroll
  for (int q=0;q<8;++q){
    a[q] += __shfl_xor(a[q], 16);
    a[q] += __shfl_xor(a[q], 32);
  }
  if (g == 0){
    if (l < 8){
      uint4 hv4 = *(const uint4*)(hcu + ((uint)node<<6) + (l<<2));
      h8 hvh = as_h8(hv4);
      float iwd = 1.f / fmaxf((float)deg - 1.f, 1.f);
      uint4 o;
      o.x = pack_h2((a[0]-(float)hvh[0])*iwd,(a[1]-(float)hvh[1])*iwd);
      o.y = pack_h2((a[2]-(float)hvh[2])*iwd,(a[3]-(float)hvh[3])*iwd);
      o.z = pack_h2((a[4]-(float)hvh[4])*iwd,(a[5]-(float)hvh[5])*iwd);
      o.w = pack_h2((a[6]-(float)hvh[6])*iwd,(a[7]-(float)hvh[7])*iwd);
      *(uint4*)(hagg + ((uint)node<<5) + (l<<2)) = o;
    } else {
      uint4 o;
      o.x = pack_h2(a[0],a[1]); o.y = pack_h2(a[2],a[3]);
      o.z = pack_h2(a[4],a[5]); o.w = pack_h2(a[6],a[7]);
      *(uint4*)(hsum + ((uint)node<<5) + ((l-8)<<2)) = o;
    }
  }
}

extern "C" void kernel_launch(void* const* d_in, const int* in_sizes, int n_in,
                              void* d_out, int out_size, void* d_ws, size_t ws_size,
                              hipStream_t stream){
  const float* content = (const float*)d_in[0];
  const float* node_emb= (const float*)d_in[1];
  const float* proj_w  = (const float*)d_in[2];
  const float* proj_b  = (const float*)d_in[3];
  const float* c0w1 = (const float*)d_in[4];
  const float* c0b1 = (const float*)d_in[5];
  const float* c0w2 = (const float*)d_in[6];
  const float* c0b2 = (const float*)d_in[7];
  const float* c1w1 = (const float*)d_in[8];
  const float* c1b1 = (const float*)d_in[9];
  const float* c1w2 = (const float*)d_in[10];
  const float* c1b2 = (const float*)d_in[11];
  const int* nid = (const int*)d_in[12];
  const int* src = (const int*)d_in[13];
  const int* dst = (const int*)d_in[14];
  float* out = (float*)d_out;
  const int n = in_sizes[12];     // 100000
  const int E = in_sizes[13];     // 1600000

  char* ws = (char*)d_ws;
  size_t off = 0;
  auto alloc = [&](size_t bytes)->char*{
    char* p = ws + off;
    off = (off + bytes + 255) & ~(size_t)255;
    return p;
  };
  const int nChunks = (E + CHUNK - 1)/CHUNK;   // 391
  const int nbkt = (n + 127) >> 7;             // 782 buckets
  half_t* h0   = (half_t*)alloc((size_t)n*64*2);
  half_t* hc   = (half_t*)alloc((size_t)n*128*2);   // [hnew(64) || hres(64)]
  half_t* hagg0= (half_t*)alloc((size_t)n*64*2);
  half_t* hagg1= (half_t*)alloc((size_t)n*64*2);
  half_t* hsum1= (half_t*)alloc((size_t)n*64*2);
  int* cnt    = (int*)alloc((size_t)n*4);
  int* col    = (int*)alloc((size_t)n*CAP*4);             // 25.6 MB
  ull* staging= (ull*)alloc((size_t)nChunks*CHUNK*8);     // 12.8 MB
  ushort* offs= (ushort*)alloc((size_t)nChunks*OSTR*2);   // 0.8 MB
  half_t* wp0 = (half_t*)alloc((size_t)256*64*2);
  half_t* wp1 = (half_t*)alloc((size_t)128*256*2);
  half_t* wp2 = (half_t*)alloc((size_t)256*64*2);
  half_t* wp3 = (half_t*)alloc((size_t)192*384*2);
  half_t* wp4 = (half_t*)alloc((size_t)384*64*2);

  const int rgrid = (n + 63)/64;   // 1563
  const int mgrid = (n + 31)/32;

  // dispatch 1: pack + binA (independent)
  front_kernel<<<80 + nChunks, 256, 0, stream>>>(
      proj_w, wp0, c0w1, wp1, c0w2, wp2, c1w1, wp3, c1w2, wp4,
      src, dst, staging, offs, E, nbkt);

  // dispatch 2: scatB || init GEMM (both depend only on dispatch 1)
  mid_kernel<<<nbkt + rgrid, 256, 0, stream>>>(
      staging, offs, cnt, col, nChunks, nbkt,
      content, wp0, proj_b, node_emb, nid, h0, n);

  // layer 0
  segsum0_kernel<<<(n+3)/4,256,0,stream>>>((const uint*)h0, cnt, col,
                                           (uint*)hagg0, (uint*)hc, n);
  mlp_kernel<128,256,64,2,EPI_LRELU_L2,true><<<mgrid,256,0,stream>>>(
      h0, hagg0, nullptr, 64,64,0, wp1, c0b1, wp2, c0b2, hc, 128, n);

  // layer 1
  segsum1_kernel<<<(n+3)/4,256,0,stream>>>((const uint*)hc, cnt, col,
                                           (uint*)hagg1, (uint*)hsum1, n);
  mlp_kernel<192,384,64,3,EPI_L2,false><<<mgrid,256,0,stream>>>(
      hc, hagg1, hsum1, 128,64,64, wp3, c1b1, wp4, c1b2, out, 64, n);
}